// Round 8
// baseline (1796.163 us; speedup 1.0000x reference)
//
#include <hip/hip_runtime.h>
#include <hip/hip_bf16.h>
#include <math.h>

// Problem dims (fixed)
#define B   64
#define NN  196
#define HH  512
#define EE  512
#define AA  512
#define VV  20000
#define LL  20

typedef __attribute__((ext_vector_type(8))) short bf16x8;
typedef __attribute__((ext_vector_type(4))) float floatx4;

__device__ __forceinline__ float tanh_fast(float x) {
  float e2 = __expf(2.f * x);
  return 1.f - 2.f / (e2 + 1.f);
}
__device__ __forceinline__ float sigmoid_fast(float x) {
  return 1.f / (1.f + __expf(-x));
}
__device__ __forceinline__ float bf2f(unsigned short u) {
  return __uint_as_float(((unsigned)u) << 16);
}
__device__ __forceinline__ unsigned short f2bf(float v) {
  __hip_bfloat16 h = __float2bfloat16(v);
  return *reinterpret_cast<unsigned short*>(&h);
}

// Chunk-XOR LDS slot, BK=64 rows (8 x 16B chunks per row):
//   c = q8 ^ (row&7); bank-group = 4c -> any 8 consecutive lanes (one write
//   phase: 8 chunks of one row; one ds_read_b128 phase: rows r..r+7 at fixed
//   chunk) get a permutation of c=0..7 -> all 32 banks, conflict-free.
//   (BK=32 version of this measured 6.4M -> 0 conflicts in round 6.)
__device__ __forceinline__ int ldsw8(int row, int q8) {
  return (row * 8 + (q8 ^ (row & 7))) * 8;
}

// ---------------------------------------------------------------------------
// bf16 MFMA GEMM: C[M,N] = Xb[M,K](bf16, row stride lda) @ Wb[N,K](bf16)^T + b
// 128x128 tile, BK=64 (2 barriers per 64-K: 32 MFMA/wave per staging phase),
// 256 thr = 4 waves, chunk-XOR LDS (conflict-free staging + frag reads).
// gridMX: 0 -> (x=n-tiles, y=m-tiles); 2 -> 1D XCD-grouped (proven: logits
// FETCH 88->24 MB).
// outMode==0: fp32 C[m*ldC+n]; ==1: logits scatter out[b,t+1,n], m=t*64+b;
// ==2: bf16 store ((ushort*)C)[m*ldC+n]
// A/B rows beyond M/N may be read (must be allocated); outputs masked.
// ---------------------------------------------------------------------------
__global__ __launch_bounds__(256) void gemm_mfma_bt(
    const unsigned short* __restrict__ Xb, const unsigned short* __restrict__ Wb,
    const float* __restrict__ bias, float* __restrict__ C,
    int M, int N, int K, int lda, int ldC, int outMode, int gridMX) {
  __shared__ unsigned short As[128 * 64];  // 16 KB
  __shared__ unsigned short Bs[128 * 64];  // 16 KB
  const int tid = threadIdx.x;
  const int lane = tid & 63;
  const int l15 = lane & 15;
  const int q = lane >> 4;        // quad 0..3
  const int wv = tid >> 6;        // wave 0..3
  const int wm = (wv >> 1) * 64;
  const int wn = (wv & 1) * 64;
  int mBase, nBase;
  if (gridMX == 2) {
    const int MT = (M + 127) >> 7, NT = (N + 127) >> 7;
    int wg = blockIdx.x;
    int xcd = wg & 7, idx = wg >> 3;
    int kk = idx / MT, mi = idx - kk * MT;
    int p = kk * 8 + xcd;
    if (p >= NT) return;
    mBase = mi * 128;
    nBase = p * 128;
  } else {
    mBase = blockIdx.y * 128;
    nBase = blockIdx.x * 128;
  }

  // staging: 1024 chunks each for A and B; thread stages 4 A + 4 B
  int sr[4], sq[4], ss[4];
#pragma unroll
  for (int i = 0; i < 4; ++i) {
    int e = tid + i * 256;
    sr[i] = e >> 3;
    sq[i] = e & 7;
    ss[i] = ldsw8(sr[i], sq[i]);
  }

  floatx4 zero = {0.f, 0.f, 0.f, 0.f};
  floatx4 acc[4][4];
#pragma unroll
  for (int i = 0; i < 4; ++i)
#pragma unroll
    for (int j = 0; j < 4; ++j) acc[i][j] = zero;

  for (int k0 = 0; k0 < K; k0 += 64) {
    uint4 av[4], bv[4];
#pragma unroll
    for (int i = 0; i < 4; ++i) {
      av[i] = *(const uint4*)(Xb + (size_t)(mBase + sr[i]) * lda + k0 + sq[i] * 8);
      bv[i] = *(const uint4*)(Wb + (size_t)(nBase + sr[i]) * K + k0 + sq[i] * 8);
    }
    __syncthreads();
#pragma unroll
    for (int i = 0; i < 4; ++i) {
      *(uint4*)&As[ss[i]] = av[i];
      *(uint4*)&Bs[ss[i]] = bv[i];
    }
    __syncthreads();
#pragma unroll
    for (int ks = 0; ks < 2; ++ks) {
      bf16x8 af[4], bfv[4];
#pragma unroll
      for (int i = 0; i < 4; ++i)
        af[i] = *(const bf16x8*)&As[ldsw8(wm + i * 16 + l15, ks * 4 + q)];
#pragma unroll
      for (int j = 0; j < 4; ++j)
        bfv[j] = *(const bf16x8*)&Bs[ldsw8(wn + j * 16 + l15, ks * 4 + q)];
#pragma unroll
      for (int i = 0; i < 4; ++i)
#pragma unroll
        for (int j = 0; j < 4; ++j)
          acc[i][j] = __builtin_amdgcn_mfma_f32_16x16x32_bf16(af[i], bfv[j],
                                                              acc[i][j], 0, 0, 0);
    }
  }

#pragma unroll
  for (int i = 0; i < 4; ++i) {
#pragma unroll
    for (int j = 0; j < 4; ++j) {
#pragma unroll
      for (int p = 0; p < 4; ++p) {
        int m = mBase + wm + i * 16 + q * 4 + p;
        int n = nBase + wn + j * 16 + l15;
        if (m < M && n < N) {
          float v = acc[i][j][p];
          if (bias) v += bias[n];
          if (outMode == 1) {
            size_t idx = (size_t)(m & 63) * ((size_t)LL * VV) +
                         (size_t)((m >> 6) + 1) * VV + n;
            C[idx] = v;
          } else if (outMode == 2) {
            ((unsigned short*)C)[(size_t)m * ldC + n] = f2bf(v);
          } else {
            C[(size_t)m * ldC + n] = v;
          }
        }
      }
    }
  }
}

// ---------------------------------------------------------------------------
// gemm_gates: gates = xcat_r[64][1024](bf16) @ Wgi[2048][1024](bf16)^T + gx,
// gate-INTERLEAVED columns (n' = 4j+g), LSTM pointwise fused in epilogue.
// Grid = 16 blocks x 256 thr; BK=64 (16 iters, 16 MFMA/wave per phase).
// Writes: c (in place), h -> xcat_w h-half (bf16) + hb_slot (bf16).
// ---------------------------------------------------------------------------
__global__ __launch_bounds__(256) void gemm_gates(
    const unsigned short* __restrict__ xcat_r,  // [128][1024] bf16
    const unsigned short* __restrict__ Wgi,     // [2048][1024] bf16 interleaved
    const float* __restrict__ gx,               // [64][2048] interleaved
    float* __restrict__ c,                      // [64][512]
    unsigned short* __restrict__ xcat_w,        // [128][1024] bf16
    unsigned short* __restrict__ hb_slot) {     // [64][512] bf16
  __shared__ unsigned short As[64 * 64];   // 8 KB
  __shared__ unsigned short Bs[128 * 64];  // 16 KB
  __shared__ float gbuf[64][132];
  const int tid = threadIdx.x;
  const int lane = tid & 63;
  const int l15 = lane & 15;
  const int q = lane >> 4;
  const int wv = tid >> 6;
  const int wn = wv * 32;
  const int nBase = blockIdx.x * 128;

  // A: 512 chunks (2/thread); B: 1024 chunks (4/thread)
  const int ar0 = tid >> 3, aq0 = tid & 7;
  const int ar1 = (tid + 256) >> 3, aq1 = (tid + 256) & 7;
  const int as0 = ldsw8(ar0, aq0), as1 = ldsw8(ar1, aq1);
  int br[4], bq[4], bs[4];
#pragma unroll
  for (int i = 0; i < 4; ++i) {
    int e = tid + i * 256;
    br[i] = e >> 3;
    bq[i] = e & 7;
    bs[i] = ldsw8(br[i], bq[i]);
  }

  floatx4 zero = {0.f, 0.f, 0.f, 0.f};
  floatx4 acc[4][2];
#pragma unroll
  for (int i = 0; i < 4; ++i)
#pragma unroll
    for (int j = 0; j < 2; ++j) acc[i][j] = zero;

  for (int k0 = 0; k0 < 1024; k0 += 64) {
    uint4 a0 = *(const uint4*)(xcat_r + (size_t)ar0 * 1024 + k0 + aq0 * 8);
    uint4 a1 = *(const uint4*)(xcat_r + (size_t)ar1 * 1024 + k0 + aq1 * 8);
    uint4 bv[4];
#pragma unroll
    for (int i = 0; i < 4; ++i)
      bv[i] = *(const uint4*)(Wgi + (size_t)(nBase + br[i]) * 1024 + k0 + bq[i] * 8);
    __syncthreads();
    *(uint4*)&As[as0] = a0;
    *(uint4*)&As[as1] = a1;
#pragma unroll
    for (int i = 0; i < 4; ++i) *(uint4*)&Bs[bs[i]] = bv[i];
    __syncthreads();
#pragma unroll
    for (int ks = 0; ks < 2; ++ks) {
      bf16x8 af[4], bfv[2];
#pragma unroll
      for (int i = 0; i < 4; ++i)
        af[i] = *(const bf16x8*)&As[ldsw8(i * 16 + l15, ks * 4 + q)];
#pragma unroll
      for (int j = 0; j < 2; ++j)
        bfv[j] = *(const bf16x8*)&Bs[ldsw8(wn + j * 16 + l15, ks * 4 + q)];
#pragma unroll
      for (int i = 0; i < 4; ++i)
#pragma unroll
        for (int j = 0; j < 2; ++j)
          acc[i][j] = __builtin_amdgcn_mfma_f32_16x16x32_bf16(af[i], bfv[j],
                                                              acc[i][j], 0, 0, 0);
    }
  }

  // acc -> gbuf[m][n]  (m local rows, n local interleaved cols)
#pragma unroll
  for (int i = 0; i < 4; ++i)
#pragma unroll
    for (int j = 0; j < 2; ++j)
#pragma unroll
      for (int p = 0; p < 4; ++p)
        gbuf[i * 16 + q * 4 + p][wn + j * 16 + l15] = acc[i][j][p];
  __syncthreads();

  // Pointwise: 2048 (b, jl) items, 8 per thread.
#pragma unroll
  for (int it = 0; it < 8; ++it) {
    int e = it * 256 + tid;
    int b = e >> 5, jl = e & 31;
    float4 gv = *(float4*)&gbuf[b][jl * 4];
    float4 gxv = *(const float4*)(gx + (size_t)b * 2048 + nBase + jl * 4);
    float ig = gv.x + gxv.x, fg = gv.y + gxv.y;
    float gg = gv.z + gxv.z, og = gv.w + gxv.w;
    int jg = (nBase >> 2) + jl;
    float cv = c[b * 512 + jg];
    float cn = sigmoid_fast(fg) * cv + sigmoid_fast(ig) * tanh_fast(gg);
    float hn = sigmoid_fast(og) * tanh_fast(cn);
    c[b * 512 + jg] = cn;
    unsigned short hbf = f2bf(hn);
    xcat_w[(size_t)b * 1024 + jg] = hbf;
    hb_slot[(size_t)b * 512 + jg] = hbf;
  }
}

// ---------------------------------------------------------------------------
// fp32 -> bf16 conversion with optional row padding (zero fill) and stride.
// ---------------------------------------------------------------------------
__global__ __launch_bounds__(256) void convert_pad(
    const float* __restrict__ src, unsigned short* __restrict__ dst,
    int srcRows, int dstRows, int srcStride, int colOff) {
  int idx = blockIdx.x * 256 + threadIdx.x;
  if (idx >= dstRows * 512) return;
  int r = idx >> 9, cc = idx & 511;
  float v = (r < srcRows) ? src[(size_t)r * srcStride + colOff + cc] : 0.f;
  dst[idx] = f2bf(v);
}

// ---------------------------------------------------------------------------
// Pack gate-interleaved weights (n' = 4j+g -> original row g*512+j):
//  Wb0i[2048][512]  = W_ih[row][0:512]          (bf16)
//  Wgi [2048][1024] = [W_hh[row] | W_ih[row][512:1024]]  (bf16)
//  bsumi[2048]      = b_ih[row] + b_hh[row]
// ---------------------------------------------------------------------------
__global__ __launch_bounds__(256) void build_weights_i(
    const float* __restrict__ W_ih, const float* __restrict__ W_hh,
    const float* __restrict__ b_ih, const float* __restrict__ b_hh,
    unsigned short* __restrict__ Wb0i, unsigned short* __restrict__ Wgi,
    float* __restrict__ bsumi) {
  int idx = blockIdx.x * 256 + threadIdx.x;
  if (idx < 2048 * 1024) {
    int np = idx >> 10, k = idx & 1023;
    int row = (np & 3) * 512 + (np >> 2);
    float v = (k < 512) ? W_hh[(size_t)row * 512 + k]
                        : W_ih[(size_t)row * 1024 + 512 + (k - 512)];
    Wgi[idx] = f2bf(v);
  }
  if (idx < 2048 * 512) {
    int np = idx >> 9, k = idx & 511;
    int row = (np & 3) * 512 + (np >> 2);
    Wb0i[idx] = f2bf(W_ih[(size_t)row * 1024 + k]);
  }
  if (idx < 2048) {
    int row = (idx & 3) * 512 + (idx >> 2);
    bsumi[idx] = b_ih[row] + b_hh[row];
  }
}

// ---------------------------------------------------------------------------
// Gather embeddings -> bf16, rows m = t*64+b, zero pad rows 1216..1279
// ---------------------------------------------------------------------------
__global__ __launch_bounds__(256) void gather_emb(
    const float* __restrict__ emb, const int* __restrict__ captions,
    unsigned short* __restrict__ embx) {
  int m = blockIdx.x;
  int tid = threadIdx.x;
  if (m >= 1216) {
    embx[(size_t)m * 512 + tid] = 0;
    embx[(size_t)m * 512 + 256 + tid] = 0;
    return;
  }
  int t = m >> 6, b = m & 63;
  int cap = captions[b * LL + t];
#pragma unroll
  for (int i = 0; i < 2; ++i) {
    float v = emb[(size_t)cap * 512 + i * 256 + tid];
    embx[(size_t)m * 512 + i * 256 + tid] = f2bf(v);
  }
}

__global__ __launch_bounds__(256) void zero_t0_kernel(float* __restrict__ out) {
  int idx = blockIdx.x * 256 + threadIdx.x;
  if (idx < B * VV) {
    int b = idx / VV, v = idx % VV;
    out[(size_t)b * ((size_t)LL * VV) + v] = 0.f;
  }
}

// ---------------------------------------------------------------------------
// Fused dec + attention (one block of 512 thr per b):
//   dec[a] = sum_k h[k]*dec_Wb[a][k] + dec_b[a]  (h from xcat h-half, LDS
//            broadcast; dec_Wb bf16 row-major, 1 KB/thread coalesced-ish)
//   scores_n = tanh(enc_projb[b,n,:] + dec) . eW + eb  (bf16 reads)
//   softmax over N; ctx = attw @ encOutb -> xcat ctx-half (bf16)
// ---------------------------------------------------------------------------
__global__ __launch_bounds__(512) void attn_score_ctx(
    const unsigned short* __restrict__ enc_projb,
    const unsigned short* __restrict__ encOutb,
    const unsigned short* __restrict__ dec_Wb,  // [512][512] bf16 row-major
    const float* __restrict__ dec_b, const float* __restrict__ eW,
    const float* __restrict__ eb, unsigned short* __restrict__ xcat_cur) {
  int b = blockIdx.x;
  int tid = threadIdx.x;
  __shared__ float hs[512];
  __shared__ float sdec[512];
  __shared__ float sw[NN];
  __shared__ float tmp[256];
  __shared__ float cp[1024];

  // ---- dec matvec ----
  hs[tid] = bf2f(xcat_cur[(size_t)b * 1024 + tid]);
  __syncthreads();
  {
    float dacc = dec_b[tid];
    const unsigned short* wr = dec_Wb + (size_t)tid * 512;
#pragma unroll 8
    for (int k0 = 0; k0 < 512; k0 += 8) {
      bf16x8 w8 = *(const bf16x8*)(wr + k0);
#pragma unroll
      for (int j = 0; j < 8; ++j)
        dacc += hs[k0 + j] * bf2f((unsigned short)w8[j]);
    }
    sdec[tid] = dacc;
  }
  __syncthreads();

  int wvv = tid >> 6, lane = tid & 63;
  float ew8[8], sd8[8];
#pragma unroll
  for (int j = 0; j < 8; ++j) {
    ew8[j] = eW[lane * 8 + j];
    sd8[j] = sdec[lane * 8 + j];
  }
  float eb0 = eb[0];
  for (int n = wvv; n < NN; n += 8) {
    const unsigned short* ep = enc_projb + ((size_t)b * NN + n) * 512 + lane * 8;
    bf16x8 v8 = *(const bf16x8*)ep;
    float a = 0.f;
#pragma unroll
    for (int j = 0; j < 8; ++j)
      a += tanh_fast(bf2f((unsigned short)v8[j]) + sd8[j]) * ew8[j];
#pragma unroll
    for (int off = 32; off; off >>= 1) a += __shfl_down(a, off, 64);
    if (lane == 0) sw[n] = a + eb0;
  }
  __syncthreads();

  // softmax over N
  float v = (tid < NN) ? sw[tid] : -1e30f;
  if (tid < 256) tmp[tid] = v;
  __syncthreads();
  for (int s = 128; s; s >>= 1) {
    if (tid < s) tmp[tid] = fmaxf(tmp[tid], tmp[tid + s]);
    __syncthreads();
  }
  float mx = tmp[0];
  __syncthreads();
  float e = (tid < NN) ? __expf(v - mx) : 0.f;
  if (tid < 256) tmp[tid] = e;
  __syncthreads();
  for (int s = 128; s; s >>= 1) {
    if (tid < s) tmp[tid] += tmp[tid + s];
    __syncthreads();
  }
  float inv = 1.f / tmp[0];
  if (tid < NN) sw[tid] = e * inv;
  __syncthreads();

  // context: bf16 enc_out, uint loads, n split across thread halves
  int half = tid >> 8, hp = tid & 255;
  const unsigned short* eo = encOutb + (size_t)b * NN * 512 + hp * 2;
  float a0 = 0.f, a1 = 0.f;
  int n0 = half * 98;
#pragma unroll 7
  for (int n = n0; n < n0 + 98; ++n) {
    float w = sw[n];
    unsigned u = *(const unsigned*)(eo + (size_t)n * 512);
    a0 += w * __uint_as_float((u & 0xffffu) << 16);
    a1 += w * __uint_as_float((u >> 16) << 16);
  }
  cp[half * 512 + hp * 2] = a0;
  cp[half * 512 + hp * 2 + 1] = a1;
  __syncthreads();
  xcat_cur[(size_t)b * 1024 + 512 + tid] = f2bf(cp[tid] + cp[512 + tid]);
}

extern "C" void kernel_launch(void* const* d_in, const int* in_sizes, int n_in,
                              void* d_out, int out_size, void* d_ws, size_t ws_size,
                              hipStream_t stream) {
  const float* enc_out  = (const float*)d_in[0];
  const int*   captions = (const int*)d_in[1];
  const float* emb      = (const float*)d_in[2];
  const float* W_ih     = (const float*)d_in[3];
  const float* W_hh     = (const float*)d_in[4];
  const float* b_ih     = (const float*)d_in[5];
  const float* b_hh     = (const float*)d_in[6];
  const float* enc_W    = (const float*)d_in[7];
  const float* enc_b    = (const float*)d_in[8];
  const float* dec_W    = (const float*)d_in[9];
  const float* dec_b    = (const float*)d_in[10];
  const float* energy_W = (const float*)d_in[11];
  const float* energy_b = (const float*)d_in[12];
  const float* fc_W     = (const float*)d_in[13];
  const float* fc_b     = (const float*)d_in[14];
  float* out = (float*)d_out;

  // Workspace layout
  float* ws = (float*)d_ws;
  float* c          = ws;                                   // 64*512
  float* gates_all  = c + 32768;                            // 19*64*2048 (interleaved)
  float* bsumi      = gates_all + (size_t)19 * 131072;      // 2048
  unsigned short* enc_projb = (unsigned short*)(bsumi + 2048); // 12544*512
  unsigned short* fcWb    = enc_projb + (size_t)12544 * 512;   // 20096*512
  unsigned short* encWb   = fcWb + (size_t)20096 * 512;        // 512*512
  unsigned short* encOutb = encWb + (size_t)512 * 512;         // 12544*512
  unsigned short* Wb0i    = encOutb + (size_t)12544 * 512;     // 2048*512
  unsigned short* Wgi     = Wb0i + (size_t)2048 * 512;         // 2048*1024
  unsigned short* dec_Wb  = Wgi + (size_t)2048 * 1024;         // 512*512
  unsigned short* embxb   = dec_Wb + (size_t)512 * 512;        // 1280*512
  unsigned short* hb      = embxb + (size_t)1280 * 512;        // 1280*512
  unsigned short* xcat2   = hb + (size_t)1280 * 512;           // 2*128*1024

  hipMemsetAsync(c, 0, 32768 * sizeof(float), stream);
  hipMemsetAsync(xcat2, 0, 2 * 128 * 1024 * sizeof(unsigned short), stream);
  hipMemsetAsync(hb + (size_t)1216 * 512, 0,
                 (size_t)64 * 512 * sizeof(unsigned short), stream);
  zero_t0_kernel<<<(B * VV + 255) / 256, 256, 0, stream>>>(out);

  build_weights_i<<<(2048 * 1024) / 256, 256, 0, stream>>>(
      W_ih, W_hh, b_ih, b_hh, Wb0i, Wgi, bsumi);

  convert_pad<<<(20096 * 512) / 256, 256, 0, stream>>>(fc_W, fcWb, 20000, 20096, 512, 0);
  convert_pad<<<(512 * 512) / 256, 256, 0, stream>>>(enc_W, encWb, 512, 512, 512, 0);
  convert_pad<<<(12544 * 512) / 256, 256, 0, stream>>>(enc_out, encOutb, 12544, 12544, 512, 0);
  convert_pad<<<(512 * 512) / 256, 256, 0, stream>>>(dec_W, dec_Wb, 512, 512, 512, 0);

  gather_emb<<<1280, 256, 0, stream>>>(emb, captions, embxb);

  // gates_x (interleaved) = embx @ Wb0i^T + bsumi   [MFMA]
  gemm_mfma_bt<<<dim3(16, 10), 256, 0, stream>>>(
      embxb, Wb0i, bsumi, gates_all, 1216, 2048, 512, 512, 2048, 0, 0);

  // enc_projb (bf16) = enc_out @ enc_W^T + enc_b   [MFMA, bf16 store]
  gemm_mfma_bt<<<dim3(4, 98), 256, 0, stream>>>(
      encOutb, encWb, enc_b, (float*)enc_projb, 12544, 512, 512, 512, 512, 2, 0);

  for (int s = 0; s < LL - 1; ++s) {
    unsigned short* xcur = xcat2 + (size_t)(s & 1) * 131072;
    unsigned short* xnxt = xcat2 + (size_t)((s + 1) & 1) * 131072;

    // 1) dec matvec + scores + softmax + context -> xcur ctx-half (bf16)
    attn_score_ctx<<<B, 512, 0, stream>>>(enc_projb, encOutb, dec_Wb, dec_b,
                                          energy_W, energy_b, xcur);

    // 2) gates (interleaved) + fused pointwise -> c, h_{s+1} -> xnxt + hb[s]
    gemm_gates<<<16, 256, 0, stream>>>(xcur, Wgi,
                                       gates_all + (size_t)s * 131072, c, xnxt,
                                       hb + (size_t)s * 32768);
  }

  // Batched logits: out[b, t+1, :] = h @ fc_W^T + fc_b  [MFMA, XCD-grouped]
  gemm_mfma_bt<<<1600, 256, 0, stream>>>(
      hb, fcWb, fc_b, out, 1216, 20000, 512, 512, 0, 1, 2);
}

// Round 9
// 1652.517 us; speedup vs baseline: 1.0869x; 1.0869x over previous
//
#include <hip/hip_runtime.h>
#include <hip/hip_bf16.h>
#include <math.h>

// Problem dims (fixed)
#define B   64
#define NN  196
#define HH  512
#define EE  512
#define AA  512
#define VV  20000
#define LL  20

typedef __attribute__((ext_vector_type(8))) short bf16x8;
typedef __attribute__((ext_vector_type(4))) float floatx4;

__device__ __forceinline__ float tanh_fast(float x) {
  float e2 = __expf(2.f * x);
  return 1.f - 2.f / (e2 + 1.f);
}
__device__ __forceinline__ float sigmoid_fast(float x) {
  return 1.f / (1.f + __expf(-x));
}
__device__ __forceinline__ float bf2f(unsigned short u) {
  return __uint_as_float(((unsigned)u) << 16);
}
__device__ __forceinline__ unsigned short f2bf(float v) {
  __hip_bfloat16 h = __float2bfloat16(v);
  return *reinterpret_cast<unsigned short*>(&h);
}

// Chunk-XOR LDS slot for BK=32 rows (4 x 16B chunks): c' = q4 ^ ((row>>1)&3).
// Measured (round 6): SQ_LDS_BANK_CONFLICT 6.4M -> 0 on the big GEMMs.
__device__ __forceinline__ int ldsw(int row, int q4) {
  return (row * 4 + (q4 ^ ((row >> 1) & 3))) * 8;
}
// Chunk-XOR for BK=64 rows (8 chunks): c' = q8 ^ (row&7). Used by gemm_gates
// (measured neutral there; REGRESSED the big logits GEMM in round 8 - do not
// use in gemm_mfma_bt).
__device__ __forceinline__ int ldsw8(int row, int q8) {
  return (row * 8 + (q8 ^ (row & 7))) * 8;
}

// ---------------------------------------------------------------------------
// bf16 MFMA GEMM: C[M,N] = Xb[M,K](bf16, row stride lda) @ Wb[N,K](bf16)^T + b
// 128x128 tile, BK=32, 256 thr = 4 waves, chunk-XOR LDS (0 bank conflicts).
// EXACT round-6 version (measured: logits 88 us, FETCH 24 MB) - round 8's
// BK=64 variant regressed it 2x (write amplification 95->255 MB).
// gridMX: 0 -> (x=n-tiles, y=m-tiles); 2 -> 1D XCD-grouped (all m-blocks of
// one n-panel on one XCD consecutively; proven FETCH 88->24 MB).
// outMode==0: fp32 C[m*ldC+n]; ==1: logits scatter out[b,t+1,n], m=t*64+b;
// ==2: bf16 store ((ushort*)C)[m*ldC+n]
// A/B rows beyond M/N may be read (must be allocated); outputs masked.
// ---------------------------------------------------------------------------
__global__ __launch_bounds__(256) void gemm_mfma_bt(
    const unsigned short* __restrict__ Xb, const unsigned short* __restrict__ Wb,
    const float* __restrict__ bias, float* __restrict__ C,
    int M, int N, int K, int lda, int ldC, int outMode, int gridMX) {
  __shared__ unsigned short As[128 * 32];
  __shared__ unsigned short Bs[128 * 32];
  const int tid = threadIdx.x;
  const int lane = tid & 63;
  const int l15 = lane & 15;
  const int q = lane >> 4;        // quad 0..3 (16B chunk col in K-slice)
  const int wv = tid >> 6;        // wave 0..3
  const int wm = (wv >> 1) * 64;  // wave m-offset in tile
  const int wn = (wv & 1) * 64;   // wave n-offset in tile
  int mBase, nBase;
  if (gridMX == 2) {
    const int MT = (M + 127) >> 7, NT = (N + 127) >> 7;
    int wg = blockIdx.x;
    int xcd = wg & 7, idx = wg >> 3;
    int kk = idx / MT, mi = idx - kk * MT;
    int p = kk * 8 + xcd;
    if (p >= NT) return;
    mBase = mi * 128;
    nBase = p * 128;
  } else {
    mBase = blockIdx.y * 128;
    nBase = blockIdx.x * 128;
  }

  // staging: 512 chunks of 16B per tile; thread stages chunks tid, tid+256
  const int c0 = tid, c1 = tid + 256;
  const int r0 = c0 >> 2, q0 = c0 & 3;
  const int r1 = c1 >> 2, q1 = c1 & 3;
  const int s0 = ldsw(r0, q0), s1 = ldsw(r1, q1);

  floatx4 zero = {0.f, 0.f, 0.f, 0.f};
  floatx4 acc[4][4];
#pragma unroll
  for (int i = 0; i < 4; ++i)
#pragma unroll
    for (int j = 0; j < 4; ++j) acc[i][j] = zero;

  for (int k0 = 0; k0 < K; k0 += 32) {
    uint4 a0 = *(const uint4*)(Xb + (size_t)(mBase + r0) * lda + k0 + q0 * 8);
    uint4 a1 = *(const uint4*)(Xb + (size_t)(mBase + r1) * lda + k0 + q1 * 8);
    uint4 b0 = *(const uint4*)(Wb + (size_t)(nBase + r0) * K + k0 + q0 * 8);
    uint4 b1 = *(const uint4*)(Wb + (size_t)(nBase + r1) * K + k0 + q1 * 8);
    __syncthreads();
    *(uint4*)&As[s0] = a0;
    *(uint4*)&As[s1] = a1;
    *(uint4*)&Bs[s0] = b0;
    *(uint4*)&Bs[s1] = b1;
    __syncthreads();
    bf16x8 af[4], bfv[4];
#pragma unroll
    for (int i = 0; i < 4; ++i)
      af[i] = *(const bf16x8*)&As[ldsw(wm + i * 16 + l15, q)];
#pragma unroll
    for (int j = 0; j < 4; ++j)
      bfv[j] = *(const bf16x8*)&Bs[ldsw(wn + j * 16 + l15, q)];
#pragma unroll
    for (int i = 0; i < 4; ++i)
#pragma unroll
      for (int j = 0; j < 4; ++j)
        acc[i][j] = __builtin_amdgcn_mfma_f32_16x16x32_bf16(af[i], bfv[j],
                                                            acc[i][j], 0, 0, 0);
  }

#pragma unroll
  for (int i = 0; i < 4; ++i) {
#pragma unroll
    for (int j = 0; j < 4; ++j) {
#pragma unroll
      for (int p = 0; p < 4; ++p) {
        int m = mBase + wm + i * 16 + q * 4 + p;
        int n = nBase + wn + j * 16 + l15;
        if (m < M && n < N) {
          float v = acc[i][j][p];
          if (bias) v += bias[n];
          if (outMode == 1) {
            size_t idx = (size_t)(m & 63) * ((size_t)LL * VV) +
                         (size_t)((m >> 6) + 1) * VV + n;
            C[idx] = v;
          } else if (outMode == 2) {
            ((unsigned short*)C)[(size_t)m * ldC + n] = f2bf(v);
          } else {
            C[(size_t)m * ldC + n] = v;
          }
        }
      }
    }
  }
}

// ---------------------------------------------------------------------------
// gemm_gates: gates = xcat_r[64][1024](bf16) @ Wgi[2048][1024](bf16)^T + gx,
// gate-INTERLEAVED columns (n' = 4j+g), LSTM pointwise fused in epilogue.
// Grid = 16 blocks x 256 thr; BK=64 (measured neutral here in round 8).
// Writes: c (in place), h -> xcat_w h-half (bf16) + hb_slot (bf16).
// ---------------------------------------------------------------------------
__global__ __launch_bounds__(256) void gemm_gates(
    const unsigned short* __restrict__ xcat_r,  // [128][1024] bf16
    const unsigned short* __restrict__ Wgi,     // [2048][1024] bf16 interleaved
    const float* __restrict__ gx,               // [64][2048] interleaved
    float* __restrict__ c,                      // [64][512]
    unsigned short* __restrict__ xcat_w,        // [128][1024] bf16
    unsigned short* __restrict__ hb_slot) {     // [64][512] bf16
  __shared__ unsigned short As[64 * 64];   // 8 KB
  __shared__ unsigned short Bs[128 * 64];  // 16 KB
  __shared__ float gbuf[64][132];
  const int tid = threadIdx.x;
  const int lane = tid & 63;
  const int l15 = lane & 15;
  const int q = lane >> 4;
  const int wv = tid >> 6;
  const int wn = wv * 32;
  const int nBase = blockIdx.x * 128;

  // A: 512 chunks (2/thread); B: 1024 chunks (4/thread)
  const int ar0 = tid >> 3, aq0 = tid & 7;
  const int ar1 = (tid + 256) >> 3, aq1 = (tid + 256) & 7;
  const int as0 = ldsw8(ar0, aq0), as1 = ldsw8(ar1, aq1);
  int br[4], bq[4], bs[4];
#pragma unroll
  for (int i = 0; i < 4; ++i) {
    int e = tid + i * 256;
    br[i] = e >> 3;
    bq[i] = e & 7;
    bs[i] = ldsw8(br[i], bq[i]);
  }

  floatx4 zero = {0.f, 0.f, 0.f, 0.f};
  floatx4 acc[4][2];
#pragma unroll
  for (int i = 0; i < 4; ++i)
#pragma unroll
    for (int j = 0; j < 2; ++j) acc[i][j] = zero;

  for (int k0 = 0; k0 < 1024; k0 += 64) {
    uint4 a0 = *(const uint4*)(xcat_r + (size_t)ar0 * 1024 + k0 + aq0 * 8);
    uint4 a1 = *(const uint4*)(xcat_r + (size_t)ar1 * 1024 + k0 + aq1 * 8);
    uint4 bv[4];
#pragma unroll
    for (int i = 0; i < 4; ++i)
      bv[i] = *(const uint4*)(Wgi + (size_t)(nBase + br[i]) * 1024 + k0 + bq[i] * 8);
    __syncthreads();
    *(uint4*)&As[as0] = a0;
    *(uint4*)&As[as1] = a1;
#pragma unroll
    for (int i = 0; i < 4; ++i) *(uint4*)&Bs[bs[i]] = bv[i];
    __syncthreads();
#pragma unroll
    for (int ks = 0; ks < 2; ++ks) {
      bf16x8 af[4], bfv[2];
#pragma unroll
      for (int i = 0; i < 4; ++i)
        af[i] = *(const bf16x8*)&As[ldsw8(i * 16 + l15, ks * 4 + q)];
#pragma unroll
      for (int j = 0; j < 2; ++j)
        bfv[j] = *(const bf16x8*)&Bs[ldsw8(wn + j * 16 + l15, ks * 4 + q)];
#pragma unroll
      for (int i = 0; i < 4; ++i)
#pragma unroll
        for (int j = 0; j < 2; ++j)
          acc[i][j] = __builtin_amdgcn_mfma_f32_16x16x32_bf16(af[i], bfv[j],
                                                              acc[i][j], 0, 0, 0);
    }
  }

  // acc -> gbuf[m][n]  (m local rows, n local interleaved cols)
#pragma unroll
  for (int i = 0; i < 4; ++i)
#pragma unroll
    for (int j = 0; j < 2; ++j)
#pragma unroll
      for (int p = 0; p < 4; ++p)
        gbuf[i * 16 + q * 4 + p][wn + j * 16 + l15] = acc[i][j][p];
  __syncthreads();

  // Pointwise: 2048 (b, jl) items, 8 per thread.
#pragma unroll
  for (int it = 0; it < 8; ++it) {
    int e = it * 256 + tid;
    int b = e >> 5, jl = e & 31;
    float4 gv = *(float4*)&gbuf[b][jl * 4];
    float4 gxv = *(const float4*)(gx + (size_t)b * 2048 + nBase + jl * 4);
    float ig = gv.x + gxv.x, fg = gv.y + gxv.y;
    float gg = gv.z + gxv.z, og = gv.w + gxv.w;
    int jg = (nBase >> 2) + jl;
    float cv = c[b * 512 + jg];
    float cn = sigmoid_fast(fg) * cv + sigmoid_fast(ig) * tanh_fast(gg);
    float hn = sigmoid_fast(og) * tanh_fast(cn);
    c[b * 512 + jg] = cn;
    unsigned short hbf = f2bf(hn);
    xcat_w[(size_t)b * 1024 + jg] = hbf;
    hb_slot[(size_t)b * 512 + jg] = hbf;
  }
}

// ---------------------------------------------------------------------------
// Fused dec + attention (one block of 512 thr per b). Unchanged (round 6/8).
// ---------------------------------------------------------------------------
__global__ __launch_bounds__(512) void attn_score_ctx(
    const unsigned short* __restrict__ enc_projb,
    const unsigned short* __restrict__ encOutb,
    const unsigned short* __restrict__ dec_Wb,  // [512][512] bf16 row-major
    const float* __restrict__ dec_b, const float* __restrict__ eW,
    const float* __restrict__ eb, unsigned short* __restrict__ xcat_cur) {
  int b = blockIdx.x;
  int tid = threadIdx.x;
  __shared__ float hs[512];
  __shared__ float sdec[512];
  __shared__ float sw[NN];
  __shared__ float tmp[256];
  __shared__ float cp[1024];

  // ---- dec matvec ----
  hs[tid] = bf2f(xcat_cur[(size_t)b * 1024 + tid]);
  __syncthreads();
  {
    float dacc = dec_b[tid];
    const unsigned short* wr = dec_Wb + (size_t)tid * 512;
#pragma unroll 8
    for (int k0 = 0; k0 < 512; k0 += 8) {
      bf16x8 w8 = *(const bf16x8*)(wr + k0);
#pragma unroll
      for (int j = 0; j < 8; ++j)
        dacc += hs[k0 + j] * bf2f((unsigned short)w8[j]);
    }
    sdec[tid] = dacc;
  }
  __syncthreads();

  int wvv = tid >> 6, lane = tid & 63;
  float ew8[8], sd8[8];
#pragma unroll
  for (int j = 0; j < 8; ++j) {
    ew8[j] = eW[lane * 8 + j];
    sd8[j] = sdec[lane * 8 + j];
  }
  float eb0 = eb[0];
  for (int n = wvv; n < NN; n += 8) {
    const unsigned short* ep = enc_projb + ((size_t)b * NN + n) * 512 + lane * 8;
    bf16x8 v8 = *(const bf16x8*)ep;
    float a = 0.f;
#pragma unroll
    for (int j = 0; j < 8; ++j)
      a += tanh_fast(bf2f((unsigned short)v8[j]) + sd8[j]) * ew8[j];
#pragma unroll
    for (int off = 32; off; off >>= 1) a += __shfl_down(a, off, 64);
    if (lane == 0) sw[n] = a + eb0;
  }
  __syncthreads();

  // softmax over N
  float v = (tid < NN) ? sw[tid] : -1e30f;
  if (tid < 256) tmp[tid] = v;
  __syncthreads();
  for (int s = 128; s; s >>= 1) {
    if (tid < s) tmp[tid] = fmaxf(tmp[tid], tmp[tid + s]);
    __syncthreads();
  }
  float mx = tmp[0];
  __syncthreads();
  float e = (tid < NN) ? __expf(v - mx) : 0.f;
  if (tid < 256) tmp[tid] = e;
  __syncthreads();
  for (int s = 128; s; s >>= 1) {
    if (tid < s) tmp[tid] += tmp[tid + s];
    __syncthreads();
  }
  float inv = 1.f / tmp[0];
  if (tid < NN) sw[tid] = e * inv;
  __syncthreads();

  // context: bf16 enc_out, uint loads, n split across thread halves
  int half = tid >> 8, hp = tid & 255;
  const unsigned short* eo = encOutb + (size_t)b * NN * 512 + hp * 2;
  float a0 = 0.f, a1 = 0.f;
  int n0 = half * 98;
#pragma unroll 7
  for (int n = n0; n < n0 + 98; ++n) {
    float w = sw[n];
    unsigned u = *(const unsigned*)(eo + (size_t)n * 512);
    a0 += w * __uint_as_float((u & 0xffffu) << 16);
    a1 += w * __uint_as_float((u >> 16) << 16);
  }
  cp[half * 512 + hp * 2] = a0;
  cp[half * 512 + hp * 2 + 1] = a1;
  __syncthreads();
  xcat_cur[(size_t)b * 1024 + 512 + tid] = f2bf(cp[tid] + cp[512 + tid]);
}

// ---------------------------------------------------------------------------
// prep_all: ALL head work in one dispatch (replaces 9 kernels + 3 memsets).
// Virtual-block dispatch: vb ranges select tasks; grid-stride over vb.
// Tasks: bf16 converts (fcW/encOut/encW/decW), gate-interleaved packs
// (Wgi/Wb0i/bsumi), embedding gather, zero-fills (out t=0, c, xcat2, hb pad).
// ---------------------------------------------------------------------------
#define VB_ENCOUT 2512   // fcWb:   [0, 2512)       20096*512 elems
#define VB_WGI    4080   // encOutb:[2512, 4080)    12544*512
#define VB_WB0I   4592   // Wgi:    [4080, 4592)    2048*1024
#define VB_ENCW   4848   // Wb0i:   [4592, 4848)    2048*512
#define VB_DECW   4912   // encWb:  [4848, 4912)    512*512
#define VB_EMB    4976   // dec_Wb: [4912, 4976)    512*512
#define VB_ZOUT   5136   // embxb:  [4976, 5136)    1280*512
#define VB_CZ     5449   // out t=0:[5136, 5449)    320000 float4
#define VB_XCZ    5457   // c zero: [5449, 5457)    8192 float4
#define VB_HBPAD  5489   // xcat2:  [5457, 5489)    32768 uint4
#define VB_BSUM   5493   // hb pad: [5489, 5493)    4096 uint4
#define VB_TOTAL  5494   // bsumi:  [5493, 5494)    2048 floats

struct PrepArgs {
  const float *fc_W, *enc_out, *W_ih, *W_hh, *b_ih, *b_hh, *enc_W, *dec_W, *emb;
  const int* captions;
  unsigned short *fcWb, *encOutb, *Wgi, *Wb0i, *encWb, *dec_Wb, *embxb, *hb,
      *xcat2;
  float *bsumi, *c, *out;
};

__global__ __launch_bounds__(256) void prep_all(PrepArgs A) {
  const int tid = threadIdx.x;
  const uint4 z4 = {0u, 0u, 0u, 0u};
  for (int vb = blockIdx.x; vb < VB_TOTAL; vb += gridDim.x) {
    if (vb < VB_ENCOUT) {  // fcWb convert (pad rows >= 20000 -> 0)
      int base = vb * 4096;
#pragma unroll 4
      for (int i = 0; i < 16; ++i) {
        int idx = base + i * 256 + tid;
        int r = idx >> 9, cc = idx & 511;
        float v = (r < 20000) ? A.fc_W[(size_t)r * 512 + cc] : 0.f;
        A.fcWb[idx] = f2bf(v);
      }
    } else if (vb < VB_WGI) {  // encOutb: direct convert
      int base = (vb - VB_ENCOUT) * 4096;
#pragma unroll 4
      for (int i = 0; i < 16; ++i) {
        int idx = base + i * 256 + tid;
        A.encOutb[idx] = f2bf(A.enc_out[idx]);
      }
    } else if (vb < VB_WB0I) {  // Wgi: interleaved [W_hh | W_ih_ctx]
      int base = (vb - VB_WGI) * 4096;
#pragma unroll 4
      for (int i = 0; i < 16; ++i) {
        int idx = base + i * 256 + tid;
        int np = idx >> 10, k = idx & 1023;
        int row = (np & 3) * 512 + (np >> 2);
        float v = (k < 512) ? A.W_hh[(size_t)row * 512 + k]
                            : A.W_ih[(size_t)row * 1024 + 512 + (k - 512)];
        A.Wgi[idx] = f2bf(v);
      }
    } else if (vb < VB_ENCW) {  // Wb0i: interleaved W_ih[:, :512]
      int base = (vb - VB_WB0I) * 4096;
#pragma unroll 4
      for (int i = 0; i < 16; ++i) {
        int idx = base + i * 256 + tid;
        int np = idx >> 9, k = idx & 511;
        int row = (np & 3) * 512 + (np >> 2);
        A.Wb0i[idx] = f2bf(A.W_ih[(size_t)row * 1024 + k]);
      }
    } else if (vb < VB_DECW) {  // encWb: direct convert
      int base = (vb - VB_ENCW) * 4096;
#pragma unroll 4
      for (int i = 0; i < 16; ++i) {
        int idx = base + i * 256 + tid;
        A.encWb[idx] = f2bf(A.enc_W[idx]);
      }
    } else if (vb < VB_EMB) {  // dec_Wb: direct convert
      int base = (vb - VB_DECW) * 4096;
#pragma unroll 4
      for (int i = 0; i < 16; ++i) {
        int idx = base + i * 256 + tid;
        A.dec_Wb[idx] = f2bf(A.dec_W[idx]);
      }
    } else if (vb < VB_ZOUT) {  // embxb gather (pad rows >= 1216 -> 0)
      int base = (vb - VB_EMB) * 4096;
#pragma unroll 4
      for (int i = 0; i < 16; ++i) {
        int idx = base + i * 256 + tid;
        int m = idx >> 9, cc = idx & 511;
        unsigned short r = 0;
        if (m < 1216) {
          int t = m >> 6, b = m & 63;
          int cap = A.captions[b * LL + t];
          r = f2bf(A.emb[(size_t)cap * 512 + cc]);
        }
        A.embxb[idx] = r;
      }
    } else if (vb < VB_CZ) {  // zero out[:, 0, :]
      int u0 = (vb - VB_ZOUT) * 1024;
      floatx4 zf = {0.f, 0.f, 0.f, 0.f};
#pragma unroll
      for (int i = 0; i < 4; ++i) {
        int u = u0 + i * 256 + tid;
        if (u < 320000) {
          int b = u / 5000, v4 = u - b * 5000;
          *(floatx4*)(A.out + (size_t)b * ((size_t)LL * VV) + v4 * 4) = zf;
        }
      }
    } else if (vb < VB_XCZ) {  // c = 0
      int u0 = (vb - VB_CZ) * 1024;
      floatx4 zf = {0.f, 0.f, 0.f, 0.f};
#pragma unroll
      for (int i = 0; i < 4; ++i) {
        int u = u0 + i * 256 + tid;
        *(floatx4*)(A.c + (size_t)u * 4) = zf;
      }
    } else if (vb < VB_HBPAD) {  // xcat2 = 0
      int u0 = (vb - VB_XCZ) * 1024;
#pragma unroll
      for (int i = 0; i < 4; ++i) {
        int u = u0 + i * 256 + tid;
        ((uint4*)A.xcat2)[u] = z4;
      }
    } else if (vb < VB_BSUM) {  // hb pad rows 1216..1279 = 0
      int u0 = (vb - VB_HBPAD) * 1024;
      uint4* hp = (uint4*)(A.hb + (size_t)1216 * 512);
#pragma unroll
      for (int i = 0; i < 4; ++i) {
        int u = u0 + i * 256 + tid;
        hp[u] = z4;
      }
    } else {  // bsumi (interleaved)
#pragma unroll
      for (int i = 0; i < 8; ++i) {
        int e = i * 256 + tid;
        int row = (e & 3) * 512 + (e >> 2);
        A.bsumi[e] = A.b_ih[row] + A.b_hh[row];
      }
    }
  }
}

extern "C" void kernel_launch(void* const* d_in, const int* in_sizes, int n_in,
                              void* d_out, int out_size, void* d_ws, size_t ws_size,
                              hipStream_t stream) {
  const float* enc_out  = (const float*)d_in[0];
  const int*   captions = (const int*)d_in[1];
  const float* emb      = (const float*)d_in[2];
  const float* W_ih     = (const float*)d_in[3];
  const float* W_hh     = (const float*)d_in[4];
  const float* b_ih     = (const float*)d_in[5];
  const float* b_hh     = (const float*)d_in[6];
  const float* enc_W    = (const float*)d_in[7];
  const float* enc_b    = (const float*)d_in[8];
  const float* dec_W    = (const float*)d_in[9];
  const float* dec_b    = (const float*)d_in[10];
  const float* energy_W = (const float*)d_in[11];
  const float* energy_b = (const float*)d_in[12];
  const float* fc_W     = (const float*)d_in[13];
  const float* fc_b     = (const float*)d_in[14];
  float* out = (float*)d_out;

  // Workspace layout
  float* ws = (float*)d_ws;
  float* c          = ws;                                   // 64*512
  float* gates_all  = c + 32768;                            // 19*64*2048 (interleaved)
  float* bsumi      = gates_all + (size_t)19 * 131072;      // 2048
  unsigned short* enc_projb = (unsigned short*)(bsumi + 2048); // 12544*512
  unsigned short* fcWb    = enc_projb + (size_t)12544 * 512;   // 20096*512
  unsigned short* encWb   = fcWb + (size_t)20096 * 512;        // 512*512
  unsigned short* encOutb = encWb + (size_t)512 * 512;         // 12544*512
  unsigned short* Wb0i    = encOutb + (size_t)12544 * 512;     // 2048*512
  unsigned short* Wgi     = Wb0i + (size_t)2048 * 512;         // 2048*1024
  unsigned short* dec_Wb  = Wgi + (size_t)2048 * 1024;         // 512*512
  unsigned short* embxb   = dec_Wb + (size_t)512 * 512;        // 1280*512
  unsigned short* hb      = embxb + (size_t)1280 * 512;        // 1280*512
  unsigned short* xcat2   = hb + (size_t)1280 * 512;           // 2*128*1024

  // Single fused head dispatch (replaces 9 kernels + 3 memsets)
  PrepArgs pa;
  pa.fc_W = fc_W;     pa.enc_out = enc_out; pa.W_ih = W_ih;  pa.W_hh = W_hh;
  pa.b_ih = b_ih;     pa.b_hh = b_hh;       pa.enc_W = enc_W;
  pa.dec_W = dec_W;   pa.emb = emb;         pa.captions = captions;
  pa.fcWb = fcWb;     pa.encOutb = encOutb; pa.Wgi = Wgi;    pa.Wb0i = Wb0i;
  pa.encWb = encWb;   pa.dec_Wb = dec_Wb;   pa.embxb = embxb;
  pa.hb = hb;         pa.xcat2 = xcat2;     pa.bsumi = bsumi;
  pa.c = c;           pa.out = out;
  prep_all<<<2560, 256, 0, stream>>>(pa);

  // gates_x (interleaved) = embx @ Wb0i^T + bsumi   [MFMA]
  gemm_mfma_bt<<<dim3(16, 10), 256, 0, stream>>>(
      embxb, Wb0i, bsumi, gates_all, 1216, 2048, 512, 512, 2048, 0, 0);

  // enc_projb (bf16) = enc_out @ enc_W^T + enc_b   [MFMA, bf16 store]
  gemm_mfma_bt<<<dim3(4, 98), 256, 0, stream>>>(
      encOutb, encWb, enc_b, (float*)enc_projb, 12544, 512, 512, 512, 512, 2, 0);

  for (int s = 0; s < LL - 1; ++s) {
    unsigned short* xcur = xcat2 + (size_t)(s & 1) * 131072;
    unsigned short* xnxt = xcat2 + (size_t)((s + 1) & 1) * 131072;

    // 1) dec matvec + scores + softmax + context -> xcur ctx-half (bf16)
    attn_score_ctx<<<B, 512, 0, stream>>>(enc_projb, encOutb, dec_Wb, dec_b,
                                          energy_W, energy_b, xcur);

    // 2) gates (interleaved) + fused pointwise -> c, h_{s+1} -> xnxt + hb[s]
    gemm_gates<<<16, 256, 0, stream>>>(xcur, Wgi,
                                       gates_all + (size_t)s * 131072, c, xnxt,
                                       hb + (size_t)s * 32768);
  }

  // Batched logits: out[b, t+1, :] = h @ fc_W^T + fc_b  [MFMA, XCD-grouped]
  gemm_mfma_bt<<<1600, 256, 0, stream>>>(
      hb, fcWb, fc_b, out, 1216, 20000, 512, 512, 0, 1, 2);
}

// Round 10
// 1550.493 us; speedup vs baseline: 1.1584x; 1.0658x over previous
//
#include <hip/hip_runtime.h>
#include <hip/hip_bf16.h>
#include <math.h>

// Problem dims (fixed)
#define B   64
#define NN  196
#define HH  512
#define EE  512
#define AA  512
#define VV  20000
#define LL  20

typedef __attribute__((ext_vector_type(8))) short bf16x8;
typedef __attribute__((ext_vector_type(4))) float floatx4;

__device__ __forceinline__ float tanh_fast(float x) {
  float e2 = __expf(2.f * x);
  return 1.f - 2.f / (e2 + 1.f);
}
__device__ __forceinline__ float sigmoid_fast(float x) {
  return 1.f / (1.f + __expf(-x));
}
__device__ __forceinline__ float bf2f(unsigned short u) {
  return __uint_as_float(((unsigned)u) << 16);
}
__device__ __forceinline__ unsigned short f2bf(float v) {
  __hip_bfloat16 h = __float2bfloat16(v);
  return *reinterpret_cast<unsigned short*>(&h);
}

// Chunk-XOR LDS slot for BK=32 rows (4 x 16B chunks): c' = q4 ^ ((row>>1)&3).
// Measured (round 6): SQ_LDS_BANK_CONFLICT 6.4M -> 0 on the big GEMMs.
__device__ __forceinline__ int ldsw(int row, int q4) {
  return (row * 4 + (q4 ^ ((row >> 1) & 3))) * 8;
}
// Chunk-XOR for BK=64 rows (8 chunks): c' = q8 ^ (row&7). gates kernel only.
__device__ __forceinline__ int ldsw8(int row, int q8) {
  return (row * 8 + (q8 ^ (row & 7))) * 8;
}

// ---------------------------------------------------------------------------
// bf16 MFMA GEMM (EXACT round-6/9 version; measured: logits 88us, FETCH 24MB,
// 0 conflicts). 128x128 tile, BK=32, 256 thr. gridMX==2: XCD-grouped 1D grid.
// outMode==0 fp32; ==1 logits scatter; ==2 bf16 store.
// ---------------------------------------------------------------------------
__global__ __launch_bounds__(256) void gemm_mfma_bt(
    const unsigned short* __restrict__ Xb, const unsigned short* __restrict__ Wb,
    const float* __restrict__ bias, float* __restrict__ C,
    int M, int N, int K, int lda, int ldC, int outMode, int gridMX) {
  __shared__ unsigned short As[128 * 32];
  __shared__ unsigned short Bs[128 * 32];
  const int tid = threadIdx.x;
  const int lane = tid & 63;
  const int l15 = lane & 15;
  const int q = lane >> 4;
  const int wv = tid >> 6;
  const int wm = (wv >> 1) * 64;
  const int wn = (wv & 1) * 64;
  int mBase, nBase;
  if (gridMX == 2) {
    const int MT = (M + 127) >> 7, NT = (N + 127) >> 7;
    int wg = blockIdx.x;
    int xcd = wg & 7, idx = wg >> 3;
    int kk = idx / MT, mi = idx - kk * MT;
    int p = kk * 8 + xcd;
    if (p >= NT) return;
    mBase = mi * 128;
    nBase = p * 128;
  } else {
    mBase = blockIdx.y * 128;
    nBase = blockIdx.x * 128;
  }

  const int c0 = tid, c1 = tid + 256;
  const int r0 = c0 >> 2, q0 = c0 & 3;
  const int r1 = c1 >> 2, q1 = c1 & 3;
  const int s0 = ldsw(r0, q0), s1 = ldsw(r1, q1);

  floatx4 zero = {0.f, 0.f, 0.f, 0.f};
  floatx4 acc[4][4];
#pragma unroll
  for (int i = 0; i < 4; ++i)
#pragma unroll
    for (int j = 0; j < 4; ++j) acc[i][j] = zero;

  for (int k0 = 0; k0 < K; k0 += 32) {
    uint4 a0 = *(const uint4*)(Xb + (size_t)(mBase + r0) * lda + k0 + q0 * 8);
    uint4 a1 = *(const uint4*)(Xb + (size_t)(mBase + r1) * lda + k0 + q1 * 8);
    uint4 b0 = *(const uint4*)(Wb + (size_t)(nBase + r0) * K + k0 + q0 * 8);
    uint4 b1 = *(const uint4*)(Wb + (size_t)(nBase + r1) * K + k0 + q1 * 8);
    __syncthreads();
    *(uint4*)&As[s0] = a0;
    *(uint4*)&As[s1] = a1;
    *(uint4*)&Bs[s0] = b0;
    *(uint4*)&Bs[s1] = b1;
    __syncthreads();
    bf16x8 af[4], bfv[4];
#pragma unroll
    for (int i = 0; i < 4; ++i)
      af[i] = *(const bf16x8*)&As[ldsw(wm + i * 16 + l15, q)];
#pragma unroll
    for (int j = 0; j < 4; ++j)
      bfv[j] = *(const bf16x8*)&Bs[ldsw(wn + j * 16 + l15, q)];
#pragma unroll
    for (int i = 0; i < 4; ++i)
#pragma unroll
      for (int j = 0; j < 4; ++j)
        acc[i][j] = __builtin_amdgcn_mfma_f32_16x16x32_bf16(af[i], bfv[j],
                                                            acc[i][j], 0, 0, 0);
  }

#pragma unroll
  for (int i = 0; i < 4; ++i) {
#pragma unroll
    for (int j = 0; j < 4; ++j) {
#pragma unroll
      for (int p = 0; p < 4; ++p) {
        int m = mBase + wm + i * 16 + q * 4 + p;
        int n = nBase + wn + j * 16 + l15;
        if (m < M && n < N) {
          float v = acc[i][j][p];
          if (bias) v += bias[n];
          if (outMode == 1) {
            size_t idx = (size_t)(m & 63) * ((size_t)LL * VV) +
                         (size_t)((m >> 6) + 1) * VV + n;
            C[idx] = v;
          } else if (outMode == 2) {
            ((unsigned short*)C)[(size_t)m * ldC + n] = f2bf(v);
          } else {
            C[(size_t)m * ldC + n] = v;
          }
        }
      }
    }
  }
}

// ---------------------------------------------------------------------------
// fused_step: ONE dispatch per timestep. 80 blocks x 512 threads, co-resident
// (80 <= 256 CUs). Producer-consumer flag sync (G16: device-scope atomics).
//  Blocks 0-63  (b=bid): dec matvec (k-chunked coalesced dec_Wp) + scores +
//                softmax + ctx -> xcur ctx-half; fence; flags[b]=target.
//  Blocks 64-79 (g=bid-64): gates GEMM [64x1024]@[128-col slice of Wgi]^T,
//                K split: h-half (0..511, no wait) -> flag wait -> ctx-half
//                (512..1023); epilogue = fused LSTM pointwise -> c, xnxt, hb.
// ---------------------------------------------------------------------------
__global__ __launch_bounds__(512) void fused_step(
    const unsigned short* __restrict__ enc_projb,
    const unsigned short* __restrict__ encOutb,
    const unsigned short* __restrict__ dec_Wp,  // [(k/8)*512+a] 8-chunk bf16
    const float* __restrict__ dec_b, const float* __restrict__ eW,
    const float* __restrict__ eb,
    const unsigned short* __restrict__ Wgi,     // [2048][1024] interleaved
    const float* __restrict__ gx,               // [64][2048] interleaved
    float* __restrict__ c,
    unsigned short* __restrict__ xcur,          // [128][1024] bf16 (h|ctx)
    unsigned short* __restrict__ xnxt,
    unsigned short* __restrict__ hb_slot,       // [64][512] bf16
    int* __restrict__ flags, int target) {
  const int tid = threadIdx.x;

  if (blockIdx.x < 64) {
    // ======================= ATTENTION PRODUCER =======================
    const int b = blockIdx.x;
    __shared__ float hs[512];
    __shared__ float sdec[512];
    __shared__ float sw[NN];
    __shared__ float tmp[256];
    __shared__ float cp[1024];

    hs[tid] = bf2f(xcur[(size_t)b * 1024 + tid]);
    __syncthreads();
    {
      float dacc = dec_b[tid];
#pragma unroll 4
      for (int kg = 0; kg < 64; ++kg) {
        bf16x8 w8 = *(const bf16x8*)(dec_Wp + (size_t)((kg << 9) + tid) * 8);
#pragma unroll
        for (int j = 0; j < 8; ++j)
          dacc += hs[kg * 8 + j] * bf2f((unsigned short)w8[j]);
      }
      sdec[tid] = dacc;
    }
    __syncthreads();

    int wvv = tid >> 6, lane = tid & 63;
    float ew8[8], sd8[8];
#pragma unroll
    for (int j = 0; j < 8; ++j) {
      ew8[j] = eW[lane * 8 + j];
      sd8[j] = sdec[lane * 8 + j];
    }
    float eb0 = eb[0];
    for (int n = wvv; n < NN; n += 8) {
      const unsigned short* ep =
          enc_projb + ((size_t)b * NN + n) * 512 + lane * 8;
      bf16x8 v8 = *(const bf16x8*)ep;
      float a = 0.f;
#pragma unroll
      for (int j = 0; j < 8; ++j)
        a += tanh_fast(bf2f((unsigned short)v8[j]) + sd8[j]) * ew8[j];
#pragma unroll
      for (int off = 32; off; off >>= 1) a += __shfl_down(a, off, 64);
      if (lane == 0) sw[n] = a + eb0;
    }
    __syncthreads();

    float v = (tid < NN) ? sw[tid] : -1e30f;
    if (tid < 256) tmp[tid] = v;
    __syncthreads();
    for (int s = 128; s; s >>= 1) {
      if (tid < s) tmp[tid] = fmaxf(tmp[tid], tmp[tid + s]);
      __syncthreads();
    }
    float mx = tmp[0];
    __syncthreads();
    float e = (tid < NN) ? __expf(v - mx) : 0.f;
    if (tid < 256) tmp[tid] = e;
    __syncthreads();
    for (int s = 128; s; s >>= 1) {
      if (tid < s) tmp[tid] += tmp[tid + s];
      __syncthreads();
    }
    float inv = 1.f / tmp[0];
    if (tid < NN) sw[tid] = e * inv;
    __syncthreads();

    int half = tid >> 8, hp = tid & 255;
    const unsigned short* eo = encOutb + (size_t)b * NN * 512 + hp * 2;
    float a0 = 0.f, a1 = 0.f;
    int n0 = half * 98;
#pragma unroll 7
    for (int n = n0; n < n0 + 98; ++n) {
      float w = sw[n];
      unsigned u = *(const unsigned*)(eo + (size_t)n * 512);
      a0 += w * __uint_as_float((u & 0xffffu) << 16);
      a1 += w * __uint_as_float((u >> 16) << 16);
    }
    cp[half * 512 + hp * 2] = a0;
    cp[half * 512 + hp * 2 + 1] = a1;
    __syncthreads();
    xcur[(size_t)b * 1024 + 512 + tid] = f2bf(cp[tid] + cp[512 + tid]);
    __threadfence();
    __syncthreads();
    if (tid == 0)
      __hip_atomic_store(&flags[b], target, __ATOMIC_RELEASE,
                         __HIP_MEMORY_SCOPE_AGENT);
  } else {
    // ======================= GATES CONSUMER =======================
    const int nBase = (blockIdx.x - 64) * 128;
    __shared__ unsigned short As[64 * 64];   // 8 KB
    __shared__ unsigned short Bs[128 * 64];  // 16 KB
    __shared__ float gbuf[64][132];          // 33 KB

    // staging indices: A 512 chunks (1/thread), B 1024 chunks (2/thread)
    const int ar = tid >> 3, aq = tid & 7;
    const int sa = ldsw8(ar, aq);
    const int br0 = tid >> 3, bq0 = tid & 7;               // e = tid
    const int br1 = (tid + 512) >> 3, bq1 = tid & 7;       // e = tid+512
    const int sb0 = ldsw8(br0, bq0), sb1 = ldsw8(br1, bq1);

    const int lane = tid & 63;
    const int l15 = lane & 15;
    const int q = lane >> 4;
    const int wv = tid >> 6;   // 0..7; MFMA on waves 0..3
    const int wn = (wv & 3) * 32;

    floatx4 zero = {0.f, 0.f, 0.f, 0.f};
    floatx4 acc[4][2];
#pragma unroll
    for (int i = 0; i < 4; ++i)
#pragma unroll
      for (int j = 0; j < 2; ++j) acc[i][j] = zero;

#pragma unroll 1
    for (int ph = 0; ph < 2; ++ph) {
      if (ph == 1) {
        // wait for all 64 ctx producers
        __syncthreads();
        if (tid < 64) {
          while (__hip_atomic_load(&flags[tid], __ATOMIC_ACQUIRE,
                                   __HIP_MEMORY_SCOPE_AGENT) < target)
            __builtin_amdgcn_s_sleep(2);
        }
        __syncthreads();
        __threadfence();
      }
      const int kLo = ph * 512;
#pragma unroll 1
      for (int k0 = kLo; k0 < kLo + 512; k0 += 64) {
        uint4 a0 = *(const uint4*)(xcur + (size_t)ar * 1024 + k0 + aq * 8);
        uint4 b0 =
            *(const uint4*)(Wgi + (size_t)(nBase + br0) * 1024 + k0 + bq0 * 8);
        uint4 b1 =
            *(const uint4*)(Wgi + (size_t)(nBase + br1) * 1024 + k0 + bq1 * 8);
        __syncthreads();
        *(uint4*)&As[sa] = a0;
        *(uint4*)&Bs[sb0] = b0;
        *(uint4*)&Bs[sb1] = b1;
        __syncthreads();
        if (tid < 256) {
#pragma unroll
          for (int ks = 0; ks < 2; ++ks) {
            bf16x8 af[4], bfv[2];
#pragma unroll
            for (int i = 0; i < 4; ++i)
              af[i] = *(const bf16x8*)&As[ldsw8(i * 16 + l15, ks * 4 + q)];
#pragma unroll
            for (int j = 0; j < 2; ++j)
              bfv[j] =
                  *(const bf16x8*)&Bs[ldsw8(wn + j * 16 + l15, ks * 4 + q)];
#pragma unroll
            for (int i = 0; i < 4; ++i)
#pragma unroll
              for (int j = 0; j < 2; ++j)
                acc[i][j] = __builtin_amdgcn_mfma_f32_16x16x32_bf16(
                    af[i], bfv[j], acc[i][j], 0, 0, 0);
          }
        }
      }
    }

    // acc -> gbuf (waves 0-3 only)
    if (tid < 256) {
#pragma unroll
      for (int i = 0; i < 4; ++i)
#pragma unroll
        for (int j = 0; j < 2; ++j)
#pragma unroll
          for (int p = 0; p < 4; ++p)
            gbuf[i * 16 + q * 4 + p][wn + j * 16 + l15] = acc[i][j][p];
    }
    __syncthreads();

    // Pointwise: 2048 (b, jl) items, 4 per thread.
#pragma unroll
    for (int it = 0; it < 4; ++it) {
      int e = it * 512 + tid;
      int b = e >> 5, jl = e & 31;
      float4 gv = *(float4*)&gbuf[b][jl * 4];
      float4 gxv = *(const float4*)(gx + (size_t)b * 2048 + nBase + jl * 4);
      float ig = gv.x + gxv.x, fg = gv.y + gxv.y;
      float gg = gv.z + gxv.z, og = gv.w + gxv.w;
      int jg = (nBase >> 2) + jl;
      float cv = c[b * 512 + jg];
      float cn = sigmoid_fast(fg) * cv + sigmoid_fast(ig) * tanh_fast(gg);
      float hn = sigmoid_fast(og) * tanh_fast(cn);
      c[b * 512 + jg] = cn;
      unsigned short hbf = f2bf(hn);
      xnxt[(size_t)b * 1024 + jg] = hbf;
      hb_slot[(size_t)b * 512 + jg] = hbf;
    }
  }
}

// ---------------------------------------------------------------------------
// prep_all: ALL head work in one dispatch. Virtual-block grid-stride.
// ---------------------------------------------------------------------------
#define VB_ENCOUT 2512
#define VB_WGI    4080
#define VB_WB0I   4592
#define VB_ENCW   4848
#define VB_DECW   4912
#define VB_EMB    4976
#define VB_ZOUT   5136
#define VB_CZ     5449
#define VB_XCZ    5457
#define VB_HBPAD  5489
#define VB_BSUM   5493
#define VB_TOTAL  5494

struct PrepArgs {
  const float *fc_W, *enc_out, *W_ih, *W_hh, *b_ih, *b_hh, *enc_W, *dec_W, *emb;
  const int* captions;
  unsigned short *fcWb, *encOutb, *Wgi, *Wb0i, *encWb, *dec_Wp, *embxb, *hb,
      *xcat2;
  float *bsumi, *c, *out;
  int* flags;
};

__global__ __launch_bounds__(256) void prep_all(PrepArgs A) {
  const int tid = threadIdx.x;
  const uint4 z4 = {0u, 0u, 0u, 0u};
  for (int vb = blockIdx.x; vb < VB_TOTAL; vb += gridDim.x) {
    if (vb < VB_ENCOUT) {  // fcWb convert (pad rows >= 20000 -> 0)
      int base = vb * 4096;
#pragma unroll 4
      for (int i = 0; i < 16; ++i) {
        int idx = base + i * 256 + tid;
        int r = idx >> 9, cc = idx & 511;
        float v = (r < 20000) ? A.fc_W[(size_t)r * 512 + cc] : 0.f;
        A.fcWb[idx] = f2bf(v);
      }
    } else if (vb < VB_WGI) {  // encOutb
      int base = (vb - VB_ENCOUT) * 4096;
#pragma unroll 4
      for (int i = 0; i < 16; ++i) {
        int idx = base + i * 256 + tid;
        A.encOutb[idx] = f2bf(A.enc_out[idx]);
      }
    } else if (vb < VB_WB0I) {  // Wgi interleaved
      int base = (vb - VB_WGI) * 4096;
#pragma unroll 4
      for (int i = 0; i < 16; ++i) {
        int idx = base + i * 256 + tid;
        int np = idx >> 10, k = idx & 1023;
        int row = (np & 3) * 512 + (np >> 2);
        float v = (k < 512) ? A.W_hh[(size_t)row * 512 + k]
                            : A.W_ih[(size_t)row * 1024 + 512 + (k - 512)];
        A.Wgi[idx] = f2bf(v);
      }
    } else if (vb < VB_ENCW) {  // Wb0i interleaved
      int base = (vb - VB_WB0I) * 4096;
#pragma unroll 4
      for (int i = 0; i < 16; ++i) {
        int idx = base + i * 256 + tid;
        int np = idx >> 9, k = idx & 511;
        int row = (np & 3) * 512 + (np >> 2);
        A.Wb0i[idx] = f2bf(A.W_ih[(size_t)row * 1024 + k]);
      }
    } else if (vb < VB_DECW) {  // encWb
      int base = (vb - VB_ENCW) * 4096;
#pragma unroll 4
      for (int i = 0; i < 16; ++i) {
        int idx = base + i * 256 + tid;
        A.encWb[idx] = f2bf(A.enc_W[idx]);
      }
    } else if (vb < VB_EMB) {  // dec_Wp: k-chunked transpose of dec_W
      int base = (vb - VB_DECW) * 4096;
#pragma unroll 4
      for (int i = 0; i < 16; ++i) {
        int idx = base + i * 256 + tid;
        int kg = idx >> 12, rem = idx & 4095;
        int a = rem >> 3, j = rem & 7;
        A.dec_Wp[idx] = f2bf(A.dec_W[(size_t)a * 512 + kg * 8 + j]);
      }
    } else if (vb < VB_ZOUT) {  // embxb gather (pad rows >= 1216 -> 0)
      int base = (vb - VB_EMB) * 4096;
#pragma unroll 4
      for (int i = 0; i < 16; ++i) {
        int idx = base + i * 256 + tid;
        int m = idx >> 9, cc = idx & 511;
        unsigned short r = 0;
        if (m < 1216) {
          int t = m >> 6, b = m & 63;
          int cap = A.captions[b * LL + t];
          r = f2bf(A.emb[(size_t)cap * 512 + cc]);
        }
        A.embxb[idx] = r;
      }
    } else if (vb < VB_CZ) {  // zero out[:, 0, :]
      int u0 = (vb - VB_ZOUT) * 1024;
      floatx4 zf = {0.f, 0.f, 0.f, 0.f};
#pragma unroll
      for (int i = 0; i < 4; ++i) {
        int u = u0 + i * 256 + tid;
        if (u < 320000) {
          int b = u / 5000, v4 = u - b * 5000;
          *(floatx4*)(A.out + (size_t)b * ((size_t)LL * VV) + v4 * 4) = zf;
        }
      }
    } else if (vb < VB_XCZ) {  // c = 0
      int u0 = (vb - VB_CZ) * 1024;
      floatx4 zf = {0.f, 0.f, 0.f, 0.f};
#pragma unroll
      for (int i = 0; i < 4; ++i) {
        int u = u0 + i * 256 + tid;
        *(floatx4*)(A.c + (size_t)u * 4) = zf;
      }
    } else if (vb < VB_HBPAD) {  // xcat2 = 0
      int u0 = (vb - VB_XCZ) * 1024;
#pragma unroll
      for (int i = 0; i < 4; ++i) {
        int u = u0 + i * 256 + tid;
        ((uint4*)A.xcat2)[u] = z4;
      }
    } else if (vb < VB_BSUM) {  // hb pad rows 1216..1279 = 0
      int u0 = (vb - VB_HBPAD) * 1024;
      uint4* hp = (uint4*)(A.hb + (size_t)1216 * 512);
#pragma unroll
      for (int i = 0; i < 4; ++i) {
        int u = u0 + i * 256 + tid;
        hp[u] = z4;
      }
    } else {  // bsumi (interleaved) + flags reset
#pragma unroll
      for (int i = 0; i < 8; ++i) {
        int e = i * 256 + tid;
        int row = (e & 3) * 512 + (e >> 2);
        A.bsumi[e] = A.b_ih[row] + A.b_hh[row];
        if (e < 64) A.flags[e] = 0;
      }
    }
  }
}

extern "C" void kernel_launch(void* const* d_in, const int* in_sizes, int n_in,
                              void* d_out, int out_size, void* d_ws, size_t ws_size,
                              hipStream_t stream) {
  const float* enc_out  = (const float*)d_in[0];
  const int*   captions = (const int*)d_in[1];
  const float* emb      = (const float*)d_in[2];
  const float* W_ih     = (const float*)d_in[3];
  const float* W_hh     = (const float*)d_in[4];
  const float* b_ih     = (const float*)d_in[5];
  const float* b_hh     = (const float*)d_in[6];
  const float* enc_W    = (const float*)d_in[7];
  const float* enc_b    = (const float*)d_in[8];
  const float* dec_W    = (const float*)d_in[9];
  const float* dec_b    = (const float*)d_in[10];
  const float* energy_W = (const float*)d_in[11];
  const float* energy_b = (const float*)d_in[12];
  const float* fc_W     = (const float*)d_in[13];
  const float* fc_b     = (const float*)d_in[14];
  float* out = (float*)d_out;

  // Workspace layout
  float* ws = (float*)d_ws;
  float* c          = ws;                                   // 64*512
  float* gates_all  = c + 32768;                            // 19*64*2048 (interleaved)
  float* bsumi      = gates_all + (size_t)19 * 131072;      // 2048
  int*   flags      = (int*)(bsumi + 2048);                 // 64
  unsigned short* enc_projb = (unsigned short*)(flags + 64);   // 12544*512
  unsigned short* fcWb    = enc_projb + (size_t)12544 * 512;   // 20096*512
  unsigned short* encWb   = fcWb + (size_t)20096 * 512;        // 512*512
  unsigned short* encOutb = encWb + (size_t)512 * 512;         // 12544*512
  unsigned short* Wb0i    = encOutb + (size_t)12544 * 512;     // 2048*512
  unsigned short* Wgi     = Wb0i + (size_t)2048 * 512;         // 2048*1024
  unsigned short* dec_Wp  = Wgi + (size_t)2048 * 1024;         // 512*512
  unsigned short* embxb   = dec_Wp + (size_t)512 * 512;        // 1280*512
  unsigned short* hb      = embxb + (size_t)1280 * 512;        // 1280*512
  unsigned short* xcat2   = hb + (size_t)1280 * 512;           // 2*128*1024

  // Single fused head dispatch
  PrepArgs pa;
  pa.fc_W = fc_W;     pa.enc_out = enc_out; pa.W_ih = W_ih;  pa.W_hh = W_hh;
  pa.b_ih = b_ih;     pa.b_hh = b_hh;       pa.enc_W = enc_W;
  pa.dec_W = dec_W;   pa.emb = emb;         pa.captions = captions;
  pa.fcWb = fcWb;     pa.encOutb = encOutb; pa.Wgi = Wgi;    pa.Wb0i = Wb0i;
  pa.encWb = encWb;   pa.dec_Wp = dec_Wp;   pa.embxb = embxb;
  pa.hb = hb;         pa.xcat2 = xcat2;     pa.bsumi = bsumi;
  pa.c = c;           pa.out = out;         pa.flags = flags;
  prep_all<<<2560, 256, 0, stream>>>(pa);

  // gates_x (interleaved) = embx @ Wb0i^T + bsumi   [MFMA]
  gemm_mfma_bt<<<dim3(16, 10), 256, 0, stream>>>(
      embxb, Wb0i, bsumi, gates_all, 1216, 2048, 512, 512, 2048, 0, 0);

  // enc_projb (bf16) = enc_out @ enc_W^T + enc_b   [MFMA, bf16 store]
  gemm_mfma_bt<<<dim3(4, 98), 256, 0, stream>>>(
      encOutb, encWb, enc_b, (float*)enc_projb, 12544, 512, 512, 512, 512, 2, 0);

  // Recurrent loop: ONE dispatch per step (80 blocks, flag-synced).
  for (int s = 0; s < LL - 1; ++s) {
    unsigned short* xcur = xcat2 + (size_t)(s & 1) * 131072;
    unsigned short* xnxt = xcat2 + (size_t)((s + 1) & 1) * 131072;
    fused_step<<<80, 512, 0, stream>>>(
        enc_projb, encOutb, dec_Wp, dec_b, energy_W, energy_b, Wgi,
        gates_all + (size_t)s * 131072, c, xcur, xnxt,
        hb + (size_t)s * 32768, flags, s + 1);
  }

  // Batched logits: out[b, t+1, :] = h @ fc_W^T + fc_b  [MFMA, XCD-grouped]
  gemm_mfma_bt<<<1600, 256, 0, stream>>>(
      hb, fcWb, fc_b, out, 1216, 20000, 512, 512, 0, 1, 2);
}